// Round 3
// baseline (578.099 us; speedup 1.0000x reference)
//
#include <hip/hip_runtime.h>
#include <math.h>

// Problem constants (from reference setup_inputs)
#define BB 16
#define CC 192
#define HH 48
#define WW 48
#define HW (HH * WW)                 // 2304
#define N_Y (BB * CC * HW)           // 7,077,888
#define IMG 768
#define N_X (BB * 3 * IMG * IMG)     // 28,311,552
#define N_Z (BB * CC * 12 * 12)      // 442,368
#define NUM_PIXELS (BB * IMG * IMG)  // 9,437,184

#define INV_SQRT2 0.7071067811865476f

// Persistent-style grid: 1024 blocks x 256 threads, each thread loops.
// Rationale: rounds 0-2 (one-shot blocks) all pinned at 3.3 TB/s combined
// read rate regardless of per-wave MLP (VGPR 36->56 A/B: occupancy halved,
// dur identical) => testing outstanding-slot-cap vs convoy-structure theory
// by adopting the known-good copy-benchmark shape: continuous pipelined
// grid-stride loops, one block reduction at the end.
#define GRID 1024
#define TPB  256
#define NTH  (GRID * TPB)            // 262,144 threads

#define GMM_U    (N_Y / 4)           // 1,769,472 float4 units
#define GMM_FULL 6                   // 6*NTH = 1,572,864 full-coverage iters
#define GMM_TAIL (GMM_U - GMM_FULL * NTH)   // 196,608 threads do a 7th unit
#define MSE_U    (N_X / 4)           // 7,077,888 float4 units
#define MSE_IT   (MSE_U / NTH)       // 27 exact iterations/thread
#define HYP_U    (N_Z / 4)           // 110,592 float4 units (< NTH)

typedef float v4f __attribute__((ext_vector_type(4)));

#define SBAR() __builtin_amdgcn_sched_barrier(0)

// Branch-free Abramowitz & Stegun 7.1.26 erf, |abs err| <= 1.5e-7.
__device__ __forceinline__ float erf_fast(float x) {
    float ax = fabsf(x);
    float t  = __builtin_amdgcn_rcpf(fmaf(0.3275911f, ax, 1.0f));
    float p  = t * fmaf(t, fmaf(t, fmaf(t, fmaf(t, 1.061405429f,
                 -1.453152027f), 1.421413741f), -0.284496736f), 0.254829592f);
    float e  = __expf(-ax * ax);
    float r  = fmaf(-p, e, 1.0f);          // erf(|x|)
    return copysignf(r, x);
}

// GMM rate:  logsumexp_k( logsoftmax(w)_k + log(pmf_k) ) collapsed to
//   rate_bits = log2(S) - log2(P) + 1
__device__ __forceinline__ float gmm_rate(float y,
                                          float w0, float w1, float w2,
                                          float m0, float m1, float m2,
                                          float s0, float s1, float s2) {
    float mw = fmaxf(w0, fmaxf(w1, w2));
    float e0 = __expf(w0 - mw), e1 = __expf(w1 - mw), e2 = __expf(w2 - mw);
    float S = e0 + e1 + e2;

    float i0 = fminf(__expf(-s0), 1e5f) * INV_SQRT2;
    float i1 = fminf(__expf(-s1), 1e5f) * INV_SQRT2;
    float i2 = fminf(__expf(-s2), 1e5f) * INV_SQRT2;

    float yu = y + 0.5f, yl = y - 0.5f;

    float d0 = erf_fast((yu - m0) * i0) - erf_fast((yl - m0) * i0);
    float d1 = erf_fast((yu - m1) * i1) - erf_fast((yl - m1) * i1);
    float d2 = erf_fast((yu - m2) * i2) - erf_fast((yl - m2) * i2);

    float P = e0 * fmaxf(d0, 2e-6f);
    P = fmaf(e1, fmaxf(d1, 2e-6f), P);
    P = fmaf(e2, fmaxf(d2, 2e-6f), P);

    return __log2f(S) - __log2f(P) + 1.0f;
}

// Load one GMM unit (y float4 + 9 param-plane float4s) into named regs.
// u in [0, GMM_U): bc = u/576 selects (b,c) plane group, hw4 = u%576.
#define GMM_LOAD(S, U) do {                                              \
    int bc_ = (U) / 576;                                                 \
    int hw_ = (U) - bc_ * 576;                                           \
    const v4f* pp_ = params4 + (size_t)bc_ * 5184 + hw_;                 \
    S##y = y4p[(U)];                                                     \
    S##0 = pp_[0 * 576]; S##1 = pp_[1 * 576]; S##2 = pp_[2 * 576];       \
    S##3 = pp_[3 * 576]; S##4 = pp_[4 * 576]; S##5 = pp_[5 * 576];       \
    S##6 = pp_[6 * 576]; S##7 = pp_[7 * 576]; S##8 = pp_[8 * 576];       \
} while (0)

#define GMM_COMP(S, ACC) do {                                            \
    float r_ = 0.0f;                                                     \
    _Pragma("unroll")                                                    \
    for (int c_ = 0; c_ < 4; ++c_)                                       \
        r_ += gmm_rate(S##y[c_], S##0[c_], S##1[c_], S##2[c_],           \
                       S##3[c_], S##4[c_], S##5[c_],                     \
                       S##6[c_], S##7[c_], S##8[c_]);                    \
    ACC += r_;                                                           \
} while (0)

__global__ void __launch_bounds__(TPB, 4)
fused_kernel(const float* __restrict__ x, const float* __restrict__ xh,
             const float* __restrict__ params, const float* __restrict__ y_hat,
             const float* __restrict__ z_hat, double* __restrict__ partial) {
    const int tid = blockIdx.x * TPB + threadIdx.x;   // [0, NTH)
    const v4f* params4 = (const v4f*)params;
    const v4f* y4p     = (const v4f*)y_hat;

    float accG = 0.0f, accM = 0.0f, accH = 0.0f;

    // ---------------- Phase 1: GMM latent rate (283 MB, LLC-heavy) --------
    // 2-deep A/B software pipeline: load(i+1) in flight across compute(i).
    {
        v4f Ay, A0, A1, A2, A3, A4, A5, A6, A7, A8;
        v4f By, B0, B1, B2, B3, B4, B5, B6, B7, B8;
        int u = tid;
        GMM_LOAD(A, u);
        GMM_LOAD(B, u + 1 * NTH); SBAR(); GMM_COMP(A, accG);
        GMM_LOAD(A, u + 2 * NTH); SBAR(); GMM_COMP(B, accG);
        GMM_LOAD(B, u + 3 * NTH); SBAR(); GMM_COMP(A, accG);
        GMM_LOAD(A, u + 4 * NTH); SBAR(); GMM_COMP(B, accG);
        GMM_LOAD(B, u + 5 * NTH); SBAR(); GMM_COMP(A, accG);
        if (tid < GMM_TAIL) { GMM_LOAD(A, u + 6 * NTH); }
        SBAR(); GMM_COMP(B, accG);
        if (tid < GMM_TAIL) { SBAR(); GMM_COMP(A, accG); }
    }

    // ---------------- Phase 2: MSE (226 MB, pure HBM, NT) ------------------
    // 3-deep rotating pipeline, 27 exact iterations per thread.
    // NT keeps x/x_hat out of LLC so params/y stay resident (FETCH_SIZE
    // confirmed ~250 MB = x+xh + ~10% params in rounds 0-2).
    {
        const v4f* x4  = (const v4f*)x;
        const v4f* xh4 = (const v4f*)xh;
        v4f pA = __builtin_nontemporal_load(x4  + tid);
        v4f qA = __builtin_nontemporal_load(xh4 + tid);
        v4f pB = __builtin_nontemporal_load(x4  + tid + NTH);
        v4f qB = __builtin_nontemporal_load(xh4 + tid + NTH);
        v4f pC, qC;
        #pragma unroll
        for (int it = 0; it < MSE_IT; ++it) {
            if (it + 2 < MSE_IT) {
                int gn = tid + (it + 2) * NTH;
                pC = __builtin_nontemporal_load(x4  + gn);
                qC = __builtin_nontemporal_load(xh4 + gn);
            }
            SBAR();
            v4f d = qA - pA;
            accM += d.x * d.x + d.y * d.y + d.z * d.z + d.w * d.w;
            pA = pB; qA = qB; pB = pC; qB = qC;   // renames after full unroll
        }
    }

    // ---------------- Phase 3: hyperlatent rate (1.8 MB) -------------------
    if (tid < HYP_U) {
        v4f z4 = ((const v4f*)z_hat)[tid];
        #pragma unroll
        for (int j = 0; j < 4; ++j) {
            float z = z4[j];
            float d = erf_fast((z + 0.5f) * INV_SQRT2)
                    - erf_fast((z - 0.5f) * INV_SQRT2);
            accH += 1.0f - __log2f(fmaxf(d, 2e-6f));
        }
    }

    // ---------------- Single block reduction (3 values) --------------------
    #pragma unroll
    for (int off = 32; off > 0; off >>= 1) {
        accG += __shfl_down(accG, off, 64);
        accM += __shfl_down(accM, off, 64);
        accH += __shfl_down(accH, off, 64);
    }
    __shared__ float sm[4][3];
    int lane = threadIdx.x & 63;
    int wid  = threadIdx.x >> 6;
    if (lane == 0) { sm[wid][0] = accG; sm[wid][1] = accM; sm[wid][2] = accH; }
    __syncthreads();
    if (threadIdx.x == 0) {
        partial[blockIdx.x] =
            (double)(sm[0][0] + sm[1][0] + sm[2][0] + sm[3][0]);
        partial[GRID + blockIdx.x] =
            (double)(sm[0][1] + sm[1][1] + sm[2][1] + sm[3][1]);
        partial[2 * GRID + blockIdx.x] =
            (double)(sm[0][2] + sm[1][2] + sm[2][2] + sm[3][2]);
    }
}

// Reduce partial segments: [0,GRID)=rate_y, [GRID,2G)=sq_err, [2G,3G)=rate_z.
__global__ void __launch_bounds__(256)
finalize_kernel(const double* __restrict__ partial, float* __restrict__ out) {
    __shared__ double sm[256];
    double seg[3];
    const int lo[3] = {0, GRID, 2 * GRID};
    const int hi[3] = {GRID, 2 * GRID, 3 * GRID};
    for (int k = 0; k < 3; ++k) {
        double a = 0.0;
        for (int i = lo[k] + threadIdx.x; i < hi[k]; i += 256) a += partial[i];
        sm[threadIdx.x] = a;
        __syncthreads();
        for (int off = 128; off > 0; off >>= 1) {
            if (threadIdx.x < (unsigned)off) sm[threadIdx.x] += sm[threadIdx.x + off];
            __syncthreads();
        }
        seg[k] = sm[0];
        __syncthreads();
    }
    if (threadIdx.x == 0) {
        double rate_y     = seg[0];
        double sq_err     = seg[1];
        double rate_z     = seg[2];
        double distortion = sq_err / (double)N_X;
        double bpp = (rate_y / (double)BB + rate_z / (double)BB) / (double)NUM_PIXELS;
        double loss = 0.01 * 255.0 * 255.0 * distortion + bpp;
        out[0] = (float)loss;
        out[1] = (float)distortion;
        out[2] = (float)bpp;
    }
}

extern "C" void kernel_launch(void* const* d_in, const int* in_sizes, int n_in,
                              void* d_out, int out_size, void* d_ws, size_t ws_size,
                              hipStream_t stream) {
    const float* x      = (const float*)d_in[0];
    const float* x_hat  = (const float*)d_in[1];
    const float* params = (const float*)d_in[2];
    const float* y_hat  = (const float*)d_in[3];
    const float* z_hat  = (const float*)d_in[4];
    float* out = (float*)d_out;
    double* partial = (double*)d_ws;   // 3*GRID doubles, all written each call

    fused_kernel<<<GRID, TPB, 0, stream>>>(x, x_hat, params, y_hat, z_hat, partial);
    finalize_kernel<<<1, 256, 0, stream>>>(partial, out);
}

// Round 4
// 576.643 us; speedup vs baseline: 1.0025x; 1.0025x over previous
//
#include <hip/hip_runtime.h>
#include <math.h>

// Problem constants (from reference setup_inputs)
#define BB 16
#define CC 192
#define HH 48
#define WW 48
#define HW (HH * WW)                 // 2304
#define N_Y (BB * CC * HW)           // 7,077,888
#define IMG 768
#define N_X (BB * 3 * IMG * IMG)     // 28,311,552
#define N_Z (BB * CC * 12 * 12)      // 442,368
#define NUM_PIXELS (BB * IMG * IMG)  // 9,437,184

#define INV_SQRT2 0.7071067811865476f

// Persistent grid: 1024 blocks x 256 threads (4 blocks/CU at 4 waves/EU).
// ROUND-4 CHANGE (only change vs round 3): pin occupancy with
// amdgpu_waves_per_eu(4,4). Round 3 evidence: VGPR_Count=64 while the fenced
// A/B GMM pipeline needs >=80 live VGPRs -> the backend's 8-waves/EU
// occupancy heuristic SPILLED the batches (WRITE_SIZE 277KB -> 331MB of
// scratch traffic on a kernel that stores 24KB). Pinning min=max=4 waves/EU
// sets the RA budget to exactly 128 VGPR: the ~110 live regs fit, no spill,
// and the scheduler stops serializing load batches (root cause of rounds
// 0-2's VGPR 36/56 convoys).
#define GRID 1024
#define TPB  256
#define NTH  (GRID * TPB)            // 262,144 threads

#define GMM_U    (N_Y / 4)           // 1,769,472 float4 units
#define GMM_FULL 6                   // 6*NTH = 1,572,864 full-coverage iters
#define GMM_TAIL (GMM_U - GMM_FULL * NTH)   // 196,608 threads do a 7th unit
#define MSE_U    (N_X / 4)           // 7,077,888 float4 units
#define MSE_IT   (MSE_U / NTH)       // 27 exact iterations/thread
#define HYP_U    (N_Z / 4)           // 110,592 float4 units (< NTH)

typedef float v4f __attribute__((ext_vector_type(4)));

#define SBAR() __builtin_amdgcn_sched_barrier(0)

// Branch-free Abramowitz & Stegun 7.1.26 erf, |abs err| <= 1.5e-7.
__device__ __forceinline__ float erf_fast(float x) {
    float ax = fabsf(x);
    float t  = __builtin_amdgcn_rcpf(fmaf(0.3275911f, ax, 1.0f));
    float p  = t * fmaf(t, fmaf(t, fmaf(t, fmaf(t, 1.061405429f,
                 -1.453152027f), 1.421413741f), -0.284496736f), 0.254829592f);
    float e  = __expf(-ax * ax);
    float r  = fmaf(-p, e, 1.0f);          // erf(|x|)
    return copysignf(r, x);
}

// GMM rate:  logsumexp_k( logsoftmax(w)_k + log(pmf_k) ) collapsed to
//   rate_bits = log2(S) - log2(P) + 1
__device__ __forceinline__ float gmm_rate(float y,
                                          float w0, float w1, float w2,
                                          float m0, float m1, float m2,
                                          float s0, float s1, float s2) {
    float mw = fmaxf(w0, fmaxf(w1, w2));
    float e0 = __expf(w0 - mw), e1 = __expf(w1 - mw), e2 = __expf(w2 - mw);
    float S = e0 + e1 + e2;

    float i0 = fminf(__expf(-s0), 1e5f) * INV_SQRT2;
    float i1 = fminf(__expf(-s1), 1e5f) * INV_SQRT2;
    float i2 = fminf(__expf(-s2), 1e5f) * INV_SQRT2;

    float yu = y + 0.5f, yl = y - 0.5f;

    float d0 = erf_fast((yu - m0) * i0) - erf_fast((yl - m0) * i0);
    float d1 = erf_fast((yu - m1) * i1) - erf_fast((yl - m1) * i1);
    float d2 = erf_fast((yu - m2) * i2) - erf_fast((yl - m2) * i2);

    float P = e0 * fmaxf(d0, 2e-6f);
    P = fmaf(e1, fmaxf(d1, 2e-6f), P);
    P = fmaf(e2, fmaxf(d2, 2e-6f), P);

    return __log2f(S) - __log2f(P) + 1.0f;
}

// Load one GMM unit (y float4 + 9 param-plane float4s) into named regs.
// u in [0, GMM_U): bc = u/576 selects (b,c) plane group, hw4 = u%576.
#define GMM_LOAD(S, U) do {                                              \
    int bc_ = (U) / 576;                                                 \
    int hw_ = (U) - bc_ * 576;                                           \
    const v4f* pp_ = params4 + (size_t)bc_ * 5184 + hw_;                 \
    S##y = y4p[(U)];                                                     \
    S##0 = pp_[0 * 576]; S##1 = pp_[1 * 576]; S##2 = pp_[2 * 576];       \
    S##3 = pp_[3 * 576]; S##4 = pp_[4 * 576]; S##5 = pp_[5 * 576];       \
    S##6 = pp_[6 * 576]; S##7 = pp_[7 * 576]; S##8 = pp_[8 * 576];       \
} while (0)

#define GMM_COMP(S, ACC) do {                                            \
    float r_ = 0.0f;                                                     \
    _Pragma("unroll")                                                    \
    for (int c_ = 0; c_ < 4; ++c_)                                       \
        r_ += gmm_rate(S##y[c_], S##0[c_], S##1[c_], S##2[c_],           \
                       S##3[c_], S##4[c_], S##5[c_],                     \
                       S##6[c_], S##7[c_], S##8[c_]);                    \
    ACC += r_;                                                           \
} while (0)

__global__ void __launch_bounds__(TPB)
__attribute__((amdgpu_waves_per_eu(4, 4)))
fused_kernel(const float* __restrict__ x, const float* __restrict__ xh,
             const float* __restrict__ params, const float* __restrict__ y_hat,
             const float* __restrict__ z_hat, double* __restrict__ partial) {
    const int tid = blockIdx.x * TPB + threadIdx.x;   // [0, NTH)
    const v4f* params4 = (const v4f*)params;
    const v4f* y4p     = (const v4f*)y_hat;

    float accG = 0.0f, accM = 0.0f, accH = 0.0f;

    // ---------------- Phase 1: GMM latent rate (283 MB, LLC-heavy) --------
    // 2-deep A/B software pipeline: load(i+1) in flight across compute(i).
    // Needs 80 VGPRs of batch data live -> requires the 128-VGPR budget.
    {
        v4f Ay, A0, A1, A2, A3, A4, A5, A6, A7, A8;
        v4f By, B0, B1, B2, B3, B4, B5, B6, B7, B8;
        int u = tid;
        GMM_LOAD(A, u);
        GMM_LOAD(B, u + 1 * NTH); SBAR(); GMM_COMP(A, accG);
        GMM_LOAD(A, u + 2 * NTH); SBAR(); GMM_COMP(B, accG);
        GMM_LOAD(B, u + 3 * NTH); SBAR(); GMM_COMP(A, accG);
        GMM_LOAD(A, u + 4 * NTH); SBAR(); GMM_COMP(B, accG);
        GMM_LOAD(B, u + 5 * NTH); SBAR(); GMM_COMP(A, accG);
        if (tid < GMM_TAIL) { GMM_LOAD(A, u + 6 * NTH); }
        SBAR(); GMM_COMP(B, accG);
        if (tid < GMM_TAIL) { SBAR(); GMM_COMP(A, accG); }
    }

    // ---------------- Phase 2: MSE (226 MB, pure HBM, NT) ------------------
    // 3-stage rotating pipeline, 27 exact iterations per thread.
    // NT keeps x/x_hat out of LLC so params/y stay resident.
    {
        const v4f* x4  = (const v4f*)x;
        const v4f* xh4 = (const v4f*)xh;
        v4f pA = __builtin_nontemporal_load(x4  + tid);
        v4f qA = __builtin_nontemporal_load(xh4 + tid);
        v4f pB = __builtin_nontemporal_load(x4  + tid + NTH);
        v4f qB = __builtin_nontemporal_load(xh4 + tid + NTH);
        v4f pC, qC;
        #pragma unroll
        for (int it = 0; it < MSE_IT; ++it) {
            if (it + 2 < MSE_IT) {
                int gn = tid + (it + 2) * NTH;
                pC = __builtin_nontemporal_load(x4  + gn);
                qC = __builtin_nontemporal_load(xh4 + gn);
            }
            SBAR();
            v4f d = qA - pA;
            accM += d.x * d.x + d.y * d.y + d.z * d.z + d.w * d.w;
            pA = pB; qA = qB; pB = pC; qB = qC;   // renames after full unroll
        }
    }

    // ---------------- Phase 3: hyperlatent rate (1.8 MB) -------------------
    if (tid < HYP_U) {
        v4f z4 = ((const v4f*)z_hat)[tid];
        #pragma unroll
        for (int j = 0; j < 4; ++j) {
            float z = z4[j];
            float d = erf_fast((z + 0.5f) * INV_SQRT2)
                    - erf_fast((z - 0.5f) * INV_SQRT2);
            accH += 1.0f - __log2f(fmaxf(d, 2e-6f));
        }
    }

    // ---------------- Single block reduction (3 values) --------------------
    #pragma unroll
    for (int off = 32; off > 0; off >>= 1) {
        accG += __shfl_down(accG, off, 64);
        accM += __shfl_down(accM, off, 64);
        accH += __shfl_down(accH, off, 64);
    }
    __shared__ float sm[4][3];
    int lane = threadIdx.x & 63;
    int wid  = threadIdx.x >> 6;
    if (lane == 0) { sm[wid][0] = accG; sm[wid][1] = accM; sm[wid][2] = accH; }
    __syncthreads();
    if (threadIdx.x == 0) {
        partial[blockIdx.x] =
            (double)(sm[0][0] + sm[1][0] + sm[2][0] + sm[3][0]);
        partial[GRID + blockIdx.x] =
            (double)(sm[0][1] + sm[1][1] + sm[2][1] + sm[3][1]);
        partial[2 * GRID + blockIdx.x] =
            (double)(sm[0][2] + sm[1][2] + sm[2][2] + sm[3][2]);
    }
}

// Reduce partial segments: [0,GRID)=rate_y, [GRID,2G)=sq_err, [2G,3G)=rate_z.
__global__ void __launch_bounds__(256)
finalize_kernel(const double* __restrict__ partial, float* __restrict__ out) {
    __shared__ double sm[256];
    double seg[3];
    const int lo[3] = {0, GRID, 2 * GRID};
    const int hi[3] = {GRID, 2 * GRID, 3 * GRID};
    for (int k = 0; k < 3; ++k) {
        double a = 0.0;
        for (int i = lo[k] + threadIdx.x; i < hi[k]; i += 256) a += partial[i];
        sm[threadIdx.x] = a;
        __syncthreads();
        for (int off = 128; off > 0; off >>= 1) {
            if (threadIdx.x < (unsigned)off) sm[threadIdx.x] += sm[threadIdx.x + off];
            __syncthreads();
        }
        seg[k] = sm[0];
        __syncthreads();
    }
    if (threadIdx.x == 0) {
        double rate_y     = seg[0];
        double sq_err     = seg[1];
        double rate_z     = seg[2];
        double distortion = sq_err / (double)N_X;
        double bpp = (rate_y / (double)BB + rate_z / (double)BB) / (double)NUM_PIXELS;
        double loss = 0.01 * 255.0 * 255.0 * distortion + bpp;
        out[0] = (float)loss;
        out[1] = (float)distortion;
        out[2] = (float)bpp;
    }
}

extern "C" void kernel_launch(void* const* d_in, const int* in_sizes, int n_in,
                              void* d_out, int out_size, void* d_ws, size_t ws_size,
                              hipStream_t stream) {
    const float* x      = (const float*)d_in[0];
    const float* x_hat  = (const float*)d_in[1];
    const float* params = (const float*)d_in[2];
    const float* y_hat  = (const float*)d_in[3];
    const float* z_hat  = (const float*)d_in[4];
    float* out = (float*)d_out;
    double* partial = (double*)d_ws;   // 3*GRID doubles, all written each call

    fused_kernel<<<GRID, TPB, 0, stream>>>(x, x_hat, params, y_hat, z_hat, partial);
    finalize_kernel<<<1, 256, 0, stream>>>(partial, out);
}